// Round 1
// baseline (452.609 us; speedup 1.0000x reference)
//
#include <hip/hip_runtime.h>
#include <math.h>

// Problem constants (fixed by reference)
constexpr int B_  = 16;
constexpr int NP_ = 512;
constexpr int NO_ = 512;
constexpr int T_  = 2048;
constexpr int NF_ = 8;
constexpr int HS_ = 256;
constexpr int TR_ = 2030;   // T - (DELAY + SKIP*(NF-1))
constexpr int TO_ = 2044;   // T - DELAY
constexpr int OPLD_ = 2048; // padded row stride for proj outputs
constexpr float EPS_ = 1e-5f;

typedef short bf16x8 __attribute__((ext_vector_type(8)));
typedef float f32x16 __attribute__((ext_vector_type(16)));

__device__ __forceinline__ unsigned short f2bf(float f) {
  union { float f; unsigned int u; } v; v.f = f;
  unsigned int r = v.u + 0x7fffu + ((v.u >> 16) & 1u);  // RNE
  return (unsigned short)(r >> 16);
}
__device__ __forceinline__ float bf2f(unsigned short u) {
  union { unsigned int u; float f; } v; v.u = ((unsigned int)u) << 16;
  return v.f;
}

// global -> LDS direct (16B/lane). LDS dest = wave-uniform base + lane*16.
typedef const __attribute__((address_space(1))) unsigned int* gas_u32;
typedef __attribute__((address_space(3))) unsigned int* las_u32;
__device__ __forceinline__ void gl16(const void* g, void* l) {
  __builtin_amdgcn_global_load_lds((gas_u32)g, (las_u32)l, 16, 0, 0);
}

// Tile geometry: [R][64] bf16 tiles, 128B rows. LDS chunk index for (row r,
// col-chunk c8) is r*8 + (c8 ^ (r&7)).  Staging: lane handling linear chunk q
// covers row r=q>>3, source col-chunk (q&7)^(r&7) -> coalesced 128B/8-lanes.
// Fragment read (row rr, k-chunk k8): elem offset rr*64 + ((k8^(rr&7))<<3).

// ---------------------------------------------------------------------------
// Transpose + cast: in f32 [b][512][2048] -> out bf16 [b][2048][512]
// ---------------------------------------------------------------------------
__global__ __launch_bounds__(256) void transpose_cvt(
    const float* __restrict__ in, unsigned short* __restrict__ outb) {
  __shared__ float tile[64][65];
  const int c0 = blockIdx.x * 64;  // t dim
  const int r0 = blockIdx.y * 64;  // p dim
  const int b  = blockIdx.z;
  const float* ib = in + (size_t)b * 512 * 2048;
  unsigned short* ob = outb + (size_t)b * 2048 * 512;
  for (int i = threadIdx.x; i < 64 * 16; i += 256) {
    const int r = i >> 4, c4 = (i & 15) * 4;
    float4 v = *(const float4*)(ib + (size_t)(r0 + r) * 2048 + c0 + c4);
    tile[r][c4 + 0] = v.x; tile[r][c4 + 1] = v.y;
    tile[r][c4 + 2] = v.z; tile[r][c4 + 3] = v.w;
  }
  __syncthreads();
  for (int i = threadIdx.x; i < 64 * 8; i += 256) {
    const int c = i >> 3, r8 = (i & 7) * 8;
    unsigned int pk[4];
    #pragma unroll
    for (int e = 0; e < 4; ++e)
      pk[e] = (unsigned int)f2bf(tile[r8 + 2 * e][c]) |
              ((unsigned int)f2bf(tile[r8 + 2 * e + 1][c]) << 16);
    *(uint4*)(ob + (size_t)(c0 + c) * 512 + r0 + r8) = *(uint4*)pk;
  }
}

// Elementwise f32 -> bf16 (n multiple of 4)
__global__ __launch_bounds__(256) void cvt_bf16(
    const float* __restrict__ in, unsigned short* __restrict__ out, int n) {
  const int i = (blockIdx.x * 256 + threadIdx.x) * 4;
  if (i < n) {
    float4 v = *(const float4*)(in + i);
    ushort4 o; o.x = f2bf(v.x); o.y = f2bf(v.y); o.z = f2bf(v.z); o.w = f2bf(v.w);
    *(ushort4*)(out + i) = o;
  }
}

// ---------------------------------------------------------------------------
// proj MFMA: out[b,hs,t] = sum_d W[hs,d]*Xt[b,t+toff,d] + bias[hs]
// 128m x 128t tile, K=512 in 8 chunks of 64. 2-phase pipeline (race-free):
//   [issue next into other buf] -> compute current -> vmcnt(0) -> barrier.
// ---------------------------------------------------------------------------
__global__ __launch_bounds__(256, 2) void proj_mfma(
    const unsigned short* __restrict__ Wbf,  // [HS][512] bf16
    const unsigned short* __restrict__ Xt,   // [B][T][512] bf16 (K contiguous)
    const float* __restrict__ bias,
    unsigned short* __restrict__ out,        // [B][HS][OPLD_] bf16
    int Tlen, int toff) {
  __shared__ char smem[65536];
  char* const Ab[2] = { smem, smem + 16384 };
  char* const Bb[2] = { smem + 32768, smem + 49152 };
  const int tid = threadIdx.x;
  const int l = tid & 63, wv = tid >> 6;
  const int h = l >> 5, tl = l & 31;
  const int mq = wv >> 1, tq = wv & 1;
  const int t0 = blockIdx.x * 128;
  const int m0 = blockIdx.y * 128;
  const int b  = blockIdx.z;
  const unsigned short* Xb = Xt + (size_t)b * T_ * 512;

  // staging descriptors (R=128: 1024 chunks, 4 instr/wave)
  int aSrc[4], bSrc[4], ldsO[4];
  #pragma unroll
  for (int i = 0; i < 4; ++i) {
    const int q = (wv << 8) + (i << 6) + l;
    const int r = q >> 3, c8s = (q & 7) ^ (r & 7);
    aSrc[i] = (m0 + r) * 512 + (c8s << 3);
    const int row = min(t0 + toff + r, T_ - 1);  // clamp: only t>=Tlen cols
    bSrc[i] = row * 512 + (c8s << 3);
    ldsO[i] = ((wv << 8) + (i << 6)) << 4;
  }

  f32x16 acc[2][2];
  #pragma unroll
  for (int i = 0; i < 2; ++i)
    #pragma unroll
    for (int jj = 0; jj < 2; ++jj)
      #pragma unroll
      for (int e = 0; e < 16; ++e) acc[i][jj][e] = 0.f;

  // prologue: stage chunk 0 into buffer 0
  #pragma unroll
  for (int i = 0; i < 4; ++i) gl16(Wbf + aSrc[i], Ab[0] + ldsO[i]);
  #pragma unroll
  for (int i = 0; i < 4; ++i) gl16(Xb + bSrc[i], Bb[0] + ldsO[i]);
  asm volatile("s_waitcnt vmcnt(0)" ::: "memory");
  __builtin_amdgcn_s_barrier();

  #pragma unroll
  for (int ps = 0; ps < 8; ++ps) {
    const int cb = ps & 1;
    if (ps < 7) {  // prefetch next chunk; target buf's readers all retired
      const int p0 = (ps + 1) << 6;
      #pragma unroll
      for (int i = 0; i < 4; ++i) gl16(Wbf + p0 + aSrc[i], Ab[cb ^ 1] + ldsO[i]);
      #pragma unroll
      for (int i = 0; i < 4; ++i) gl16(Xb + p0 + bSrc[i], Bb[cb ^ 1] + ldsO[i]);
    }
    const unsigned short* As = (const unsigned short*)Ab[cb];
    const unsigned short* Bs = (const unsigned short*)Bb[cb];
    #pragma unroll
    for (int s = 0; s < 4; ++s) {
      const int k8 = 2 * s + h;
      bf16x8 af[2], bfr[2];
      #pragma unroll
      for (int mt = 0; mt < 2; ++mt) {
        const int rm = 64 * mq + 32 * mt + tl;
        af[mt] = *(const bf16x8*)(As + rm * 64 + ((k8 ^ (rm & 7)) << 3));
      }
      #pragma unroll
      for (int nt = 0; nt < 2; ++nt) {
        const int rt = 64 * tq + 32 * nt + tl;
        bfr[nt] = *(const bf16x8*)(Bs + rt * 64 + ((k8 ^ (rt & 7)) << 3));
      }
      #pragma unroll
      for (int mt = 0; mt < 2; ++mt)
        #pragma unroll
        for (int nt = 0; nt < 2; ++nt)
          acc[mt][nt] = __builtin_amdgcn_mfma_f32_32x32x16_bf16(
              af[mt], bfr[nt], acc[mt][nt], 0, 0, 0);
    }
    asm volatile("s_waitcnt vmcnt(0)" ::: "memory");
    __builtin_amdgcn_s_barrier();
  }
  // epilogue: D layout col=lane&31 (t), row=(r&3)+8*(r>>2)+4*(lane>>5) (m)
  #pragma unroll
  for (int mt = 0; mt < 2; ++mt)
    #pragma unroll
    for (int nt = 0; nt < 2; ++nt)
      #pragma unroll
      for (int r = 0; r < 16; ++r) {
        const int hs = m0 + 64 * mq + 32 * mt + (r & 3) + 8 * (r >> 2) + 4 * h;
        const int t  = t0 + 64 * tq + 32 * nt + tl;
        if (t < Tlen)
          out[((size_t)b * HS_ + hs) * OPLD_ + t] = f2bf(acc[mt][nt][r] + bias[hs]);
      }
}

// ---------------------------------------------------------------------------
// inner MFMA v2: per block (b, kf-pair, t-tile 256), 8 waves (512 thr).
// Wave wv owns t-cols [t0+32*wv, t0+32*wv+32).
//
//  Phase A (per m-chunk mc of 64): Q[f][m][t] = sum_p tri[kf0+f][m][p]*pred[p][t]
//    - pred slices are WAVE-PRIVATE ([32 t][64 p] per buf): no barrier needed,
//      3-buffer rotation -> depth-2 counted-vmcnt pipeline.
//    - tri [2 kf][64 m][64 p] is SHARED: double-buffered, staged right after
//      the per-phase barrier (previous readers retired), depth-1.
//    - per-wave issue order guarantees uniform counted waits:
//        mc-top: TOO(3/4), tri0(2), pred0(4), pred1(4)
//        body(ps): tri(ps+1)(2), pred(ps+2)(4)
//      -> at every ps<7: s_waitcnt vmcnt(4) retires exactly {pred(ps), tri(ps)}
//         (plus TOO at ps=0); ps=7: vmcnt(0). No full drain in steady state.
//  Phase B: Q -> bf16 -> per-wave LDS (grouped layout, aliases pred bufs 0/1,
//    dead by then), banded MFMA S[t'][t] += too^T * Q  (atoo shared across kf).
//    TOO rows [0,224) shared in LDS; rows [224,288) are only read by waves 6/7
//    -> staged privately into (dead) tri buf0 during ps==7, drained by the
//    phase-B vmcnt(0). No barriers anywhere in phase B / extraction.
// Extraction: inner[b,j,kf,t] = S[(t-tc)+4+2j][t], tc = t0+32*wv.
// LDS map (156KB): PRED [0,98304) wv*12288+buf*4096 | TRI [98304,131072)
//   +buf*16384+f*8192 | TOO [131072,159744) rows<224. 1 block/CU, 2 waves/SIMD.
// ---------------------------------------------------------------------------
__global__ __launch_bounds__(512, 2) void inner_mfma(
    const unsigned short* __restrict__ pred_t,  // [B][T][NP] bf16
    const unsigned short* __restrict__ too_t,   // [B][T][NO] bf16
    const unsigned short* __restrict__ tri_bf,  // [NF][NO][NP] bf16
    float* __restrict__ inner) {                // [B][NF][NF][TR] f32
  __shared__ char smem[159744];
  const int tid = threadIdx.x;
  const int l = tid & 63, wv = tid >> 6;
  const int h = l >> 5, tl = l & 31;
  const int t0 = blockIdx.x * 256;
  const int kf0 = blockIdx.y * 2;
  const int b  = blockIdx.z;
  const unsigned short* predB = pred_t + (size_t)b * T_ * NP_;
  const unsigned short* tooB  = too_t  + (size_t)b * T_ * NO_;
  const unsigned short* triK  = tri_bf + (size_t)kf0 * NO_ * NP_;

  char* const predW = smem + wv * 12288;        // this wave's 3 pred bufs
  char* const triB0 = smem + 98304;             // tri buf0 (also tail alias)
  char* const tooS  = smem + 131072;            // too rows [0,224)

  // ---- staging descriptors (units: shorts for global, bytes for LDS)
  int pSrc[4];
  #pragma unroll
  for (int i = 0; i < 4; ++i) {
    const int q = (i << 6) + l;                 // [0,256) chunks of wave slice
    const int rl = q >> 3, c8s = (q & 7) ^ (rl & 7);
    pSrc[i] = (t0 + (wv << 5) + rl) * NP_ + (c8s << 3);
  }
  int tSrc[2];
  #pragma unroll
  for (int i = 0; i < 2; ++i) {
    const int q = (wv << 7) + (i << 6) + l;     // [0,1024) = 2kf x 64 x 8
    const int f = q >> 9, qq = q & 511;
    const int r = qq >> 3, c8s = (qq & 7) ^ (r & 7);
    tSrc[i] = f * (NO_ * NP_) + r * NP_ + (c8s << 3);
  }
  int oSrc[4];
  #pragma unroll
  for (int i = 0; i < 4; ++i) {
    const int q = (i < 3) ? (i * 512 + (wv << 6) + l) : (1536 + (wv << 6) + l);
    const int r = q >> 3, c8s = (q & 7) ^ (r & 7);
    oSrc[i] = min(t0 + r, T_ - 1) * NO_ + (c8s << 3);
  }

  f32x16 Sacc[2][2];   // [kf][ct]
  #pragma unroll
  for (int f = 0; f < 2; ++f)
    #pragma unroll
    for (int ct = 0; ct < 2; ++ct)
      #pragma unroll
      for (int e = 0; e < 16; ++e) Sacc[f][ct][e] = 0.f;

  for (int mc = 0; mc < 8; ++mc) {
    const int m0 = mc << 6;
    const int mOff = m0 * NP_;
    // all waves retired phase-B reads (TOO, tri-buf0 tails, QSw) of prev mc
    __builtin_amdgcn_s_barrier();
    // issue order matters for vmcnt counting: TOO, tri0, pred0, pred1
    #pragma unroll
    for (int i = 0; i < 3; ++i)
      gl16(tooB + m0 + oSrc[i], tooS + ((i * 512 + (wv << 6)) << 4));
    if (wv < 4)
      gl16(tooB + m0 + oSrc[3], tooS + ((1536 + (wv << 6)) << 4));
    #pragma unroll
    for (int i = 0; i < 2; ++i)
      gl16(triK + mOff + tSrc[i], triB0 + (((wv << 7) + (i << 6)) << 4));
    #pragma unroll
    for (int i = 0; i < 4; ++i) gl16(predB + pSrc[i], predW + (i << 10));
    #pragma unroll
    for (int i = 0; i < 4; ++i) gl16(predB + 64 + pSrc[i], predW + 4096 + (i << 10));

    f32x16 Qacc[2][2];  // [kf][mt]
    #pragma unroll
    for (int f = 0; f < 2; ++f)
      #pragma unroll
      for (int mt = 0; mt < 2; ++mt)
        #pragma unroll
        for (int e = 0; e < 16; ++e) Qacc[f][mt][e] = 0.f;

    #pragma unroll
    for (int ps = 0; ps < 8; ++ps) {
      const int cb = ps & 1;        // tri buf
      const int pb = ps % 3;        // pred buf
      // counted wait: retires {pred(ps), tri(ps)} (and TOO at ps=0),
      // leaves pred(ps+1) in flight. ps=7 drains all.
      if (ps < 7) asm volatile("s_waitcnt vmcnt(4)" ::: "memory");
      else        asm volatile("s_waitcnt vmcnt(0)" ::: "memory");
      __builtin_amdgcn_s_barrier();
      if (ps < 7) {  // tri(ps+1): prev readers of target buf retired at barrier
        const int p1 = (ps + 1) << 6;
        #pragma unroll
        for (int i = 0; i < 2; ++i)
          gl16(triK + mOff + p1 + tSrc[i],
               triB0 + (cb ^ 1) * 16384 + (((wv << 7) + (i << 6)) << 4));
      }
      if (ps < 6) {  // pred(ps+2): wave-private buffer, depth-2
        const int p2 = (ps + 2) << 6;
        const int pb2 = (ps + 2) % 3;
        #pragma unroll
        for (int i = 0; i < 4; ++i)
          gl16(predB + p2 + pSrc[i], predW + pb2 * 4096 + (i << 10));
      }
      if (ps == 7) {  // TOO tail rows [224,288): private to waves 6/7, into
                      // dead tri buf0 (last read at ps=6, all waves past bar 7)
        if (wv == 6) {
          #pragma unroll
          for (int i = 0; i < 4; ++i) {
            const int q = (i << 6) + l;
            const int r = 224 + (q >> 3), c8s = (q & 7) ^ (r & 7);
            gl16(tooB + m0 + min(t0 + r, T_ - 1) * NO_ + (c8s << 3),
                 triB0 + (i << 10));
          }
        } else if (wv == 7) {
          #pragma unroll
          for (int i = 0; i < 8; ++i) {
            const int q = (i << 6) + l;
            const int r = 224 + (q >> 3), c8s = (q & 7) ^ (r & 7);
            gl16(tooB + m0 + min(t0 + r, T_ - 1) * NO_ + (c8s << 3),
                 triB0 + 4096 + (i << 10));
          }
        }
      }
      // compute: 16 MFMA (2 kf x 2 mt x 4 s)
      const char* triS0 = triB0 + cb * 16384;
      const char* triS1 = triS0 + 8192;
      const char* ppS   = predW + pb * 4096;
      __builtin_amdgcn_s_setprio(1);
      #pragma unroll
      for (int s = 0; s < 4; ++s) {
        const int k8 = 2 * s + h;
        const bf16x8 bp = *(const bf16x8*)(ppS + (((tl << 3) + (k8 ^ (tl & 7))) << 4));
        #pragma unroll
        for (int mt = 0; mt < 2; ++mt) {
          const int rm = (mt << 5) + tl;
          const int co = ((rm << 3) + (k8 ^ (tl & 7))) << 4;
          const bf16x8 a0 = *(const bf16x8*)(triS0 + co);
          const bf16x8 a1 = *(const bf16x8*)(triS1 + co);
          Qacc[0][mt] = __builtin_amdgcn_mfma_f32_32x32x16_bf16(a0, bp, Qacc[0][mt], 0, 0, 0);
          Qacc[1][mt] = __builtin_amdgcn_mfma_f32_32x32x16_bf16(a1, bp, Qacc[1][mt], 0, 0, 0);
        }
      }
      __builtin_amdgcn_s_setprio(0);
    }
    // ---- Phase B (no barriers: all remaining traffic is wave-private or
    // stable-shared). Drain the tail loads (no-op for waves 0..5).
    asm volatile("s_waitcnt vmcnt(0)" ::: "memory");
    #pragma unroll
    for (int f = 0; f < 2; ++f) {
      unsigned short* QSw = (unsigned short*)(predW + (f << 12));  // pred bufs 0/1: dead
      #pragma unroll
      for (int mt = 0; mt < 2; ++mt)
        #pragma unroll
        for (int rp = 0; rp < 8; ++rp) {
          const int r = rp << 1;
          const int m = (mt << 5) + (r & 3) + ((r >> 2) << 3) + (h << 2);
          const int c8 = m >> 3, ml = m & 7;
          const int rX = (tl & 24) | ((tl ^ c8) & 7);
          const unsigned int pk = (unsigned int)f2bf(Qacc[f][mt][r]) |
                                  ((unsigned int)f2bf(Qacc[f][mt][r + 1]) << 16);
          *(unsigned int*)(QSw + (((c8 << 5) + rX) << 3) + ml) = pk;
        }
    }
    #pragma unroll
    for (int s = 0; s < 4; ++s) {  // K=64 (m) in 4 steps of 16
      const int k8 = 2 * s + h;
      bf16x8 atoo[2];
      #pragma unroll
      for (int ct = 0; ct < 2; ++ct) {
        const int rbase = (wv << 5) + (ct << 5);   // too row t' = t0 + rbase + tl
        const char* tb = (rbase < 224)
            ? (tooS + rbase * 128)
            : (triB0 + ((wv == 7) ? 4096 : 0) + (rbase - 224) * 128);
        atoo[ct] = *(const bf16x8*)(tb + tl * 128 + ((k8 ^ (tl & 7)) << 4));
      }
      const int rqX = (tl & 24) | ((tl ^ k8) & 7);
      #pragma unroll
      for (int f = 0; f < 2; ++f) {
        const bf16x8 bq = *(const bf16x8*)((const unsigned short*)(predW + (f << 12)) +
                                           (((k8 << 5) + rqX) << 3));
        #pragma unroll
        for (int ct = 0; ct < 2; ++ct)
          Sacc[f][ct] = __builtin_amdgcn_mfma_f32_32x32x16_bf16(atoo[ct], bq, Sacc[f][ct], 0, 0, 0);
      }
    }
  }
  // ---- extraction: S[c][t], c=(t-tc)+4+2j, tc = t0+32*wv (wave-private SW)
  const int tglob = t0 + (wv << 5) + tl;
  float* SW = (float*)predW;  // 8KB per wave
  #pragma unroll
  for (int f = 0; f < 2; ++f) {
    #pragma unroll
    for (int ct = 0; ct < 2; ++ct)
      #pragma unroll
      for (int r = 0; r < 16; ++r) {
        const int cc = (ct << 5) + (r & 3) + ((r >> 2) << 3) + (h << 2);
        SW[(cc << 5) + tl] = Sacc[f][ct][r];
      }
    if (tglob < TR_) {
      #pragma unroll
      for (int jj = 0; jj < 4; ++jj) {
        const int j = (jj << 1) + h;
        const float v = SW[((tl + 4 + 2 * j) << 5) + tl];
        inner[(((size_t)b * NF_ + j) * NF_ + (kf0 + f)) * TR_ + tglob] = v;
      }
    }
  }
}

// ---------------------------------------------------------------------------
// BN partial stats (bf16 proj inputs, stride OPLD_). Deterministic.
// ---------------------------------------------------------------------------
__global__ __launch_bounds__(256) void bn_stats(
    const unsigned short* __restrict__ op, const unsigned short* __restrict__ pp,
    float* __restrict__ partials) {
  const int hh = blockIdx.x, b = blockIdx.y;
  const unsigned short* oprow = op + ((size_t)b * HS_ + hh) * OPLD_;
  const unsigned short* pprow = pp + ((size_t)b * HS_ + hh) * OPLD_;
  float s = 0.f, s2 = 0.f;
  for (int t = threadIdx.x; t < TR_; t += 256) {
    const float pv = bf2f(pprow[t]);
    #pragma unroll
    for (int j = 0; j < NF_; ++j) {
      float r = bf2f(oprow[t + 2 * j]) + pv;
      r = fmaxf(r, 0.f);
      s += r; s2 += r * r;
    }
  }
  __shared__ float red[256], red2[256];
  red[threadIdx.x] = s; red2[threadIdx.x] = s2;
  __syncthreads();
  for (int st = 128; st > 0; st >>= 1) {
    if (threadIdx.x < st) {
      red[threadIdx.x]  += red[threadIdx.x + st];
      red2[threadIdx.x] += red2[threadIdx.x + st];
    }
    __syncthreads();
  }
  if (threadIdx.x == 0) {
    partials[b * HS_ + hh]            = red[0];
    partials[B_ * HS_ + b * HS_ + hh] = red2[0];
  }
}

__global__ __launch_bounds__(256) void bn_finalize(
    const float* __restrict__ partials, const float* __restrict__ gamma,
    const float* __restrict__ beta, const float* __restrict__ w_out,
    const float* __restrict__ b_out, float* __restrict__ w_eff,
    float* __restrict__ cvec) {
  const int hh = threadIdx.x;
  float s = 0.f, s2 = 0.f;
  for (int b = 0; b < B_; ++b) {
    s  += partials[b * HS_ + hh];
    s2 += partials[B_ * HS_ + b * HS_ + hh];
  }
  const float cnt  = (float)B_ * NF_ * TR_;
  const float mean = s / cnt;
  const float var  = s2 / cnt - mean * mean;
  const float scale = gamma[hh] * rsqrtf(var + EPS_);
  const float shift = beta[hh] - mean * scale;
  #pragma unroll
  for (int k = 0; k < NF_; ++k) w_eff[k * HS_ + hh] = w_out[k * HS_ + hh] * scale;
  __shared__ float red[256];
  for (int k = 0; k < NF_; ++k) {
    red[hh] = w_out[k * HS_ + hh] * shift;
    __syncthreads();
    for (int st = 128; st > 0; st >>= 1) {
      if (hh < st) red[hh] += red[hh + st];
      __syncthreads();
    }
    if (hh == 0) cvec[k] = b_out[k] + red[0];
    __syncthreads();
  }
}

// ---------------------------------------------------------------------------
// head + log-softmax diagonal, fused. One block per (t-chunk 256, b, j-half).
// ---------------------------------------------------------------------------
__global__ __launch_bounds__(256) void head_final(
    const unsigned short* __restrict__ op, const unsigned short* __restrict__ pp,
    const float* __restrict__ w_eff, const float* __restrict__ cvec,
    const float* __restrict__ inner, float* __restrict__ part3) {
  __shared__ float opS[288 * 20];  // [col][hh] col=t-t0 in [0,288)
  __shared__ float ppS[256 * 20];
  __shared__ float weS[8][256];
  __shared__ float red[4][5];
  const int tid = threadIdx.x;
  const int t0 = blockIdx.x * 256;
  const int b  = blockIdx.y;
  const int jh = blockIdx.z;  // j half
  for (int i = tid; i < 8 * 256; i += 256) weS[i >> 8][i & 255] = w_eff[i];
  float acc[4][8] = {};
  const unsigned short* opb = op + (size_t)b * HS_ * OPLD_;
  const unsigned short* ppb = pp + (size_t)b * HS_ * OPLD_;
  for (int hc = 0; hc < 16; ++hc) {
    const int h0 = hc << 4;
    __syncthreads();
    for (int idx = tid; idx < 576; idx += 256) {
      const int r = idx / 36, cc = (idx - r * 36) << 3;
      const int g = min(t0 + cc, OPLD_ - 8);
      uint4 v = *(const uint4*)(opb + (size_t)(h0 + r) * OPLD_ + g);
      #pragma unroll
      for (int e = 0; e < 4; ++e) {
        const unsigned int u = (&v.x)[e];
        opS[(cc + 2 * e) * 20 + r]     = bf2f((unsigned short)(u & 0xffffu));
        opS[(cc + 2 * e + 1) * 20 + r] = bf2f((unsigned short)(u >> 16));
      }
    }
    for (int idx = tid; idx < 512; idx += 256) {
      const int r = idx >> 5, cc = (idx & 31) << 3;
      uint4 v = *(const uint4*)(ppb + (size_t)(h0 + r) * OPLD_ + t0 + cc);
      #pragma unroll
      for (int e = 0; e < 4; ++e) {
        const unsigned int u = (&v.x)[e];
        ppS[(cc + 2 * e) * 20 + r]     = bf2f((unsigned short)(u & 0xffffu));
        ppS[(cc + 2 * e + 1) * 20 + r] = bf2f((unsigned short)(u >> 16));
      }
    }
    __syncthreads();
    float pv[16];
    #pragma unroll
    for (int i = 0; i < 4; ++i) {
      float4 q = *(const float4*)(ppS + tid * 20 + 4 * i);
      pv[4 * i + 0] = q.x; pv[4 * i + 1] = q.y;
      pv[4 * i + 2] = q.z; pv[4 * i + 3] = q.w;
    }
    #pragma unroll
    for (int jj = 0; jj < 4; ++jj) {
      const int col = tid + 2 * ((jh << 2) + jj);
      #pragma unroll
      for (int i = 0; i < 4; ++i) {
        float4 ov = *(const float4*)(opS + col * 20 + 4 * i);
        #pragma unroll
        for (int e = 0; e < 4; ++e) {
          const float r = fmaxf((&ov.x)[e] + pv[4 * i + e], 0.f);
          #pragma unroll
          for (int k = 0; k < 8; ++k) acc[jj][k] += weS[k][h0 + 4 * i + e] * r;
        }
      }
    }
  }
  const int t = t0 + tid;
  float sj[4];
  #pragma unroll
  for (int jj = 0; jj < 4; ++jj) {
    if (t < TR_) {
      const int j = (jh << 2) + jj;
      float v[8]; float mx = -1e30f;
      #pragma unroll
      for (int k = 0; k < 8; ++k) {
        v[k] = acc[jj][k] + cvec[k] +
               inner[(((size_t)b * NF_ + j) * NF_ + k) * TR_ + t];
        mx = fmaxf(mx, v[k]);
      }
      float se = 0.f;
      #pragma unroll
      for (int k = 0; k < 8; ++k) se += expf(v[k] - mx);
      sj[jj] = v[j] - mx - logf(se);
    } else sj[jj] = 0.f;
  }
  #pragma unroll
  for (int jj = 0; jj < 4; ++jj)
    #pragma unroll
    for (int off = 32; off > 0; off >>= 1) sj[jj] += __shfl_down(sj[jj], off);
  if ((tid & 63) == 0) {
    const int wv = tid >> 6;
    #pragma unroll
    for (int jj = 0; jj < 4; ++jj) red[jj][wv] = sj[jj];
  }
  __syncthreads();
  if (tid < 4) {
    const float s = red[tid][0] + red[tid][1] + red[tid][2] + red[tid][3];
    const int j = (jh << 2) + tid;
    part3[(j * B_ + b) * 8 + blockIdx.x] = s;
  }
}

__global__ void final_out(const float* __restrict__ part3, float* __restrict__ out) {
  const int j = threadIdx.x;
  if (j < NF_) {
    float s = 0.f;
    for (int i = 0; i < B_ * 8; ++i) s += part3[j * B_ * 8 + i];
    out[j] = s / ((float)B_ * (float)TR_);
  }
}

// ---------------------------------------------------------------------------
extern "C" void kernel_launch(void* const* d_in, const int* in_sizes, int n_in,
                              void* d_out, int out_size, void* d_ws, size_t ws_size,
                              hipStream_t stream) {
  const float* predictor = (const float*)d_in[0];
  const float* to_order  = (const float*)d_in[1];
  const float* trilinear = (const float*)d_in[2];
  const float* w_o   = (const float*)d_in[3];
  const float* b_o   = (const float*)d_in[4];
  const float* w_p   = (const float*)d_in[5];
  const float* b_p   = (const float*)d_in[6];
  const float* bn_g  = (const float*)d_in[7];
  const float* bn_b  = (const float*)d_in[8];
  const float* w_out = (const float*)d_in[9];
  const float* b_out = (const float*)d_in[10];
  float* out = (float*)d_out;

  char* w = (char*)d_ws;
  unsigned short* pred_t = (unsigned short*)w; w += (size_t)B_ * T_ * NP_ * 2;
  unsigned short* too_t  = (unsigned short*)w; w += (size_t)B_ * T_ * NO_ * 2;
  unsigned short* tri_bf = (unsigned short*)w; w += (size_t)NF_ * NO_ * NP_ * 2;
  unsigned short* wo_bf  = (unsigned short*)w; w += (size_t)HS_ * NO_ * 2;
  unsigned short* wp_bf  = (unsigned short*)w; w += (size_t)HS_ * NP_ * 2;
  unsigned short* o_proj = (unsigned short*)w; w += (size_t)B_ * HS_ * OPLD_ * 2;
  unsigned short* p_proj = (unsigned short*)w; w += (size_t)B_ * HS_ * OPLD_ * 2;
  float* inner    = (float*)w; w += (size_t)B_ * NF_ * NF_ * TR_ * 4;
  float* partials = (float*)w; w += (size_t)2 * B_ * HS_ * 4;
  float* w_eff    = (float*)w; w += (size_t)NF_ * HS_ * 4;
  float* cvec     = (float*)w; w += 256;
  float* part3    = (float*)w; w += (size_t)NF_ * B_ * 8 * 4;

  transpose_cvt<<<dim3(32, 8, 16), 256, 0, stream>>>(predictor, pred_t);
  transpose_cvt<<<dim3(32, 8, 16), 256, 0, stream>>>(to_order, too_t);
  cvt_bf16<<<2048, 256, 0, stream>>>(trilinear, tri_bf, NF_ * NO_ * NP_);
  cvt_bf16<<<128, 256, 0, stream>>>(w_o, wo_bf, HS_ * NO_);
  cvt_bf16<<<128, 256, 0, stream>>>(w_p, wp_bf, HS_ * NP_);

  proj_mfma<<<dim3(16, 2, 16), 256, 0, stream>>>(wo_bf, too_t, b_o, o_proj, TO_, 4);
  proj_mfma<<<dim3(16, 2, 16), 256, 0, stream>>>(wp_bf, pred_t, b_p, p_proj, TR_, 0);

  inner_mfma<<<dim3(8, 4, 16), 512, 0, stream>>>(pred_t, too_t, tri_bf, inner);

  bn_stats<<<dim3(HS_, B_), 256, 0, stream>>>(o_proj, p_proj, partials);
  bn_finalize<<<1, 256, 0, stream>>>(partials, bn_g, bn_b, w_out, b_out, w_eff, cvec);
  head_final<<<dim3(8, B_, 2), 256, 0, stream>>>(o_proj, p_proj, w_eff, cvec, inner, part3);
  final_out<<<1, 64, 0, stream>>>(part3, out);
}

// Round 2
// 338.246 us; speedup vs baseline: 1.3381x; 1.3381x over previous
//
#include <hip/hip_runtime.h>
#include <math.h>

// Problem constants (fixed by reference)
constexpr int B_  = 16;
constexpr int NP_ = 512;
constexpr int NO_ = 512;
constexpr int T_  = 2048;
constexpr int NF_ = 8;
constexpr int HS_ = 256;
constexpr int TR_ = 2030;   // T - (DELAY + SKIP*(NF-1))
constexpr int TO_ = 2044;   // T - DELAY
constexpr int OPLD_ = 2048; // padded row stride for proj outputs
constexpr float EPS_ = 1e-5f;

typedef short bf16x8 __attribute__((ext_vector_type(8)));
typedef float f32x16 __attribute__((ext_vector_type(16)));

__device__ __forceinline__ unsigned short f2bf(float f) {
  union { float f; unsigned int u; } v; v.f = f;
  unsigned int r = v.u + 0x7fffu + ((v.u >> 16) & 1u);  // RNE
  return (unsigned short)(r >> 16);
}
__device__ __forceinline__ float bf2f(unsigned short u) {
  union { unsigned int u; float f; } v; v.u = ((unsigned int)u) << 16;
  return v.f;
}

// global -> LDS direct (16B/lane). LDS dest = wave-uniform base + lane*16.
typedef const __attribute__((address_space(1))) unsigned int* gas_u32;
typedef __attribute__((address_space(3))) unsigned int* las_u32;
__device__ __forceinline__ void gl16(const void* g, void* l) {
  __builtin_amdgcn_global_load_lds((gas_u32)g, (las_u32)l, 16, 0, 0);
}

// Tile geometry: [R][64] bf16 tiles, 128B rows. LDS chunk index for (row r,
// col-chunk c8) is r*8 + (c8 ^ (r&7)).  Staging: lane handling linear chunk q
// covers row r=q>>3, source col-chunk (q&7)^(r&7) -> coalesced 128B/8-lanes.
// Fragment read (row rr, k-chunk k8): elem offset rr*64 + ((k8^(rr&7))<<3).

// ---------------------------------------------------------------------------
// Transpose + cast: in f32 [b][512][2048] -> out bf16 [b][2048][512]
// ---------------------------------------------------------------------------
__global__ __launch_bounds__(256) void transpose_cvt(
    const float* __restrict__ in, unsigned short* __restrict__ outb) {
  __shared__ float tile[64][65];
  const int c0 = blockIdx.x * 64;  // t dim
  const int r0 = blockIdx.y * 64;  // p dim
  const int b  = blockIdx.z;
  const float* ib = in + (size_t)b * 512 * 2048;
  unsigned short* ob = outb + (size_t)b * 2048 * 512;
  for (int i = threadIdx.x; i < 64 * 16; i += 256) {
    const int r = i >> 4, c4 = (i & 15) * 4;
    float4 v = *(const float4*)(ib + (size_t)(r0 + r) * 2048 + c0 + c4);
    tile[r][c4 + 0] = v.x; tile[r][c4 + 1] = v.y;
    tile[r][c4 + 2] = v.z; tile[r][c4 + 3] = v.w;
  }
  __syncthreads();
  for (int i = threadIdx.x; i < 64 * 8; i += 256) {
    const int c = i >> 3, r8 = (i & 7) * 8;
    unsigned int pk[4];
    #pragma unroll
    for (int e = 0; e < 4; ++e)
      pk[e] = (unsigned int)f2bf(tile[r8 + 2 * e][c]) |
              ((unsigned int)f2bf(tile[r8 + 2 * e + 1][c]) << 16);
    *(uint4*)(ob + (size_t)(c0 + c) * 512 + r0 + r8) = *(uint4*)pk;
  }
}

// Elementwise f32 -> bf16 (n multiple of 4)
__global__ __launch_bounds__(256) void cvt_bf16(
    const float* __restrict__ in, unsigned short* __restrict__ out, int n) {
  const int i = (blockIdx.x * 256 + threadIdx.x) * 4;
  if (i < n) {
    float4 v = *(const float4*)(in + i);
    ushort4 o; o.x = f2bf(v.x); o.y = f2bf(v.y); o.z = f2bf(v.z); o.w = f2bf(v.w);
    *(ushort4*)(out + i) = o;
  }
}

// ---------------------------------------------------------------------------
// proj MFMA: out[b,hs,t] = sum_d W[hs,d]*Xt[b,t+toff,d] + bias[hs]
// 128m x 128t tile, K=512 in 8 chunks of 64. 2-phase pipeline (race-free):
//   [issue next into other buf] -> compute current -> vmcnt(0) -> barrier.
// ---------------------------------------------------------------------------
__global__ __launch_bounds__(256, 2) void proj_mfma(
    const unsigned short* __restrict__ Wbf,  // [HS][512] bf16
    const unsigned short* __restrict__ Xt,   // [B][T][512] bf16 (K contiguous)
    const float* __restrict__ bias,
    unsigned short* __restrict__ out,        // [B][HS][OPLD_] bf16
    int Tlen, int toff) {
  __shared__ char smem[65536];
  char* const Ab[2] = { smem, smem + 16384 };
  char* const Bb[2] = { smem + 32768, smem + 49152 };
  const int tid = threadIdx.x;
  const int l = tid & 63, wv = tid >> 6;
  const int h = l >> 5, tl = l & 31;
  const int mq = wv >> 1, tq = wv & 1;
  const int t0 = blockIdx.x * 128;
  const int m0 = blockIdx.y * 128;
  const int b  = blockIdx.z;
  const unsigned short* Xb = Xt + (size_t)b * T_ * 512;

  // staging descriptors (R=128: 1024 chunks, 4 instr/wave)
  int aSrc[4], bSrc[4], ldsO[4];
  #pragma unroll
  for (int i = 0; i < 4; ++i) {
    const int q = (wv << 8) + (i << 6) + l;
    const int r = q >> 3, c8s = (q & 7) ^ (r & 7);
    aSrc[i] = (m0 + r) * 512 + (c8s << 3);
    const int row = min(t0 + toff + r, T_ - 1);  // clamp: only t>=Tlen cols
    bSrc[i] = row * 512 + (c8s << 3);
    ldsO[i] = ((wv << 8) + (i << 6)) << 4;
  }

  f32x16 acc[2][2];
  #pragma unroll
  for (int i = 0; i < 2; ++i)
    #pragma unroll
    for (int jj = 0; jj < 2; ++jj)
      #pragma unroll
      for (int e = 0; e < 16; ++e) acc[i][jj][e] = 0.f;

  // prologue: stage chunk 0 into buffer 0
  #pragma unroll
  for (int i = 0; i < 4; ++i) gl16(Wbf + aSrc[i], Ab[0] + ldsO[i]);
  #pragma unroll
  for (int i = 0; i < 4; ++i) gl16(Xb + bSrc[i], Bb[0] + ldsO[i]);
  asm volatile("s_waitcnt vmcnt(0)" ::: "memory");
  __builtin_amdgcn_s_barrier();

  #pragma unroll
  for (int ps = 0; ps < 8; ++ps) {
    const int cb = ps & 1;
    if (ps < 7) {  // prefetch next chunk; target buf's readers all retired
      const int p0 = (ps + 1) << 6;
      #pragma unroll
      for (int i = 0; i < 4; ++i) gl16(Wbf + p0 + aSrc[i], Ab[cb ^ 1] + ldsO[i]);
      #pragma unroll
      for (int i = 0; i < 4; ++i) gl16(Xb + p0 + bSrc[i], Bb[cb ^ 1] + ldsO[i]);
    }
    const unsigned short* As = (const unsigned short*)Ab[cb];
    const unsigned short* Bs = (const unsigned short*)Bb[cb];
    #pragma unroll
    for (int s = 0; s < 4; ++s) {
      const int k8 = 2 * s + h;
      bf16x8 af[2], bfr[2];
      #pragma unroll
      for (int mt = 0; mt < 2; ++mt) {
        const int rm = 64 * mq + 32 * mt + tl;
        af[mt] = *(const bf16x8*)(As + rm * 64 + ((k8 ^ (rm & 7)) << 3));
      }
      #pragma unroll
      for (int nt = 0; nt < 2; ++nt) {
        const int rt = 64 * tq + 32 * nt + tl;
        bfr[nt] = *(const bf16x8*)(Bs + rt * 64 + ((k8 ^ (rt & 7)) << 3));
      }
      #pragma unroll
      for (int mt = 0; mt < 2; ++mt)
        #pragma unroll
        for (int nt = 0; nt < 2; ++nt)
          acc[mt][nt] = __builtin_amdgcn_mfma_f32_32x32x16_bf16(
              af[mt], bfr[nt], acc[mt][nt], 0, 0, 0);
    }
    asm volatile("s_waitcnt vmcnt(0)" ::: "memory");
    __builtin_amdgcn_s_barrier();
  }
  // epilogue: D layout col=lane&31 (t), row=(r&3)+8*(r>>2)+4*(lane>>5) (m)
  #pragma unroll
  for (int mt = 0; mt < 2; ++mt)
    #pragma unroll
    for (int nt = 0; nt < 2; ++nt)
      #pragma unroll
      for (int r = 0; r < 16; ++r) {
        const int hs = m0 + 64 * mq + 32 * mt + (r & 3) + 8 * (r >> 2) + 4 * h;
        const int t  = t0 + 64 * tq + 32 * nt + tl;
        if (t < Tlen)
          out[((size_t)b * HS_ + hs) * OPLD_ + t] = f2bf(acc[mt][nt][r] + bias[hs]);
      }
}

// ---------------------------------------------------------------------------
// inner MFMA v3: v1 skeleton (4 waves, t-tile 128, 2 blocks/CU) + kf-PAIRING.
// Per block (b, kf-pair, t-tile 128). 8 m-chunks of 64:
//  Phase A: Q[f][m][t] = sum_p tri[kf0+f][m][p]*pred[b][p][t]  (MFMA, K=512,
//    2-phase dbuf via global_load_lds, row-major XOR-swizzled LDS).
//    One bp fragment feeds 4 MFMAs (2 kf x 2 mt): frag reads/MFMA 1.5 -> 1.25,
//    and pred/too staging bytes per MFMA halve (grid 2048 -> 1024 blocks).
//  Phase B: Q -> bf16 -> per-wave LDS (grouped layout, aliases Pb[f] wave
//    slice; dead), banded MFMA S[f][t'][t] += too^T * Q[f] (atoo shared
//    across kf). TOO rows [0,96) resident; rows [96,160) staged into dead
//    Tb[0] at ps==7, drained by that phase's vmcnt(0)+barrier (race-free).
// Extraction: inner[b,j,kf0+f,t] = S[f][(t-tc)+4+2j][t].
// LDS 76KB: Pb 2x16K | Tb 2x16K (Tb[0] doubles as TOO tail) | TOOM 12K.
// 2 blocks/CU (152KB), 8 waves/CU. Acc regs: Qacc[2][2]+Sacc[2][2]=128 (v2-
// proven footprint at 2 waves/SIMD).
// ---------------------------------------------------------------------------
__global__ __launch_bounds__(256, 2) void inner_mfma(
    const unsigned short* __restrict__ pred_t,  // [B][T][NP] bf16
    const unsigned short* __restrict__ too_t,   // [B][T][NO] bf16
    const unsigned short* __restrict__ tri_bf,  // [NF][NO][NP] bf16
    float* __restrict__ inner) {                // [B][NF][NF][TR] f32
  __shared__ char smem[77824];
  char* const Pb[2] = { smem, smem + 16384 };           // predS dbuf (R=128)
  char* const Tb[2] = { smem + 32768, smem + 49152 };   // triS dbuf (2kf x 64)
  char* const TOOM  = smem + 65536;                     // too rows [0,96)
  char* const TAIL  = smem + 32768;                     // =Tb[0]: rows [96,160)
  const int tid = threadIdx.x;
  const int l = tid & 63, wv = tid >> 6;
  const int h = l >> 5, tl = l & 31;
  const int t0 = blockIdx.x * 128;
  const int kf0 = blockIdx.y * 2;
  const int b  = blockIdx.z;
  const unsigned short* predB = pred_t + (size_t)b * T_ * NP_;
  const unsigned short* tooB  = too_t  + (size_t)b * T_ * NO_;
  const unsigned short* triK  = tri_bf + (size_t)kf0 * NO_ * NP_;

  // staging descriptors
  int pSrc[4], pLds[4];
  #pragma unroll
  for (int i = 0; i < 4; ++i) {
    const int q = (wv << 8) + (i << 6) + l;
    const int r = q >> 3, c8s = (q & 7) ^ (r & 7);
    pSrc[i] = (t0 + r) * NP_ + (c8s << 3);
    pLds[i] = ((wv << 8) + (i << 6)) << 4;
  }
  int tSrc[4], tLds[4];  // 2 kf x [64 m][64 p]: 1024 chunks, 4/wave
  #pragma unroll
  for (int i = 0; i < 4; ++i) {
    const int q = (wv << 8) + (i << 6) + l;
    const int f = q >> 9, qq = q & 511;
    const int r = qq >> 3, c8s = (qq & 7) ^ (r & 7);
    tSrc[i] = f * (NO_ * NP_) + r * NP_ + (c8s << 3);
    tLds[i] = ((wv << 8) + (i << 6)) << 4;
  }
  int oSrc[3], oLds[3];  // too rows [0,96): 768 chunks, 3/wave
  #pragma unroll
  for (int i = 0; i < 3; ++i) {
    const int q = wv * 192 + (i << 6) + l;
    const int r = q >> 3, c8s = (q & 7) ^ (r & 7);
    oSrc[i] = (t0 + r) * NO_ + (c8s << 3);  // t0+r <= 2015 < T_: no clamp
    oLds[i] = (wv * 192 + (i << 6)) << 4;
  }
  // tail rows [96,160): staged by waves 2,3 (4 gl16 each) at ps==7
  int aSrcT[4], aLdsT[4];
  {
    const int ws = (wv >= 2) ? (wv - 2) : 0;
    #pragma unroll
    for (int i = 0; i < 4; ++i) {
      const int q = (ws << 8) + (i << 6) + l;
      const int r = 96 + (q >> 3), c8s = (q & 7) ^ (r & 7);
      aSrcT[i] = min(t0 + r, T_ - 1) * NO_ + (c8s << 3);  // clamped rows feed
      aLdsT[i] = ((ws << 8) + (i << 6)) << 4;             // unused diagonals
    }
  }

  f32x16 Sacc[2][2];   // [kf][ct]
  #pragma unroll
  for (int f = 0; f < 2; ++f)
    #pragma unroll
    for (int ct = 0; ct < 2; ++ct)
      #pragma unroll
      for (int e = 0; e < 16; ++e) Sacc[f][ct][e] = 0.f;

  for (int mc = 0; mc < 8; ++mc) {
    const int m0 = mc << 6;
    const int mOff = m0 * NP_;
    // all waves finished Phase B reads (TOOM, TAIL, QS in Pb) of prev chunk
    __builtin_amdgcn_s_barrier();
    #pragma unroll
    for (int i = 0; i < 3; ++i) gl16(tooB + m0 + oSrc[i], TOOM + oLds[i]);
    #pragma unroll
    for (int i = 0; i < 4; ++i) gl16(triK + mOff + tSrc[i], Tb[0] + tLds[i]);
    #pragma unroll
    for (int i = 0; i < 4; ++i) gl16(predB + pSrc[i], Pb[0] + pLds[i]);
    asm volatile("s_waitcnt vmcnt(0)" ::: "memory");
    __builtin_amdgcn_s_barrier();

    f32x16 Qacc[2][2];  // [kf][mt]
    #pragma unroll
    for (int f = 0; f < 2; ++f)
      #pragma unroll
      for (int mt = 0; mt < 2; ++mt)
        #pragma unroll
        for (int e = 0; e < 16; ++e) Qacc[f][mt][e] = 0.f;

    #pragma unroll
    for (int ps = 0; ps < 8; ++ps) {
      const int cb = ps & 1;
      if (ps < 7) {  // prefetch next p-chunk; target buf's readers retired
        const int p1 = (ps + 1) << 6;
        #pragma unroll
        for (int i = 0; i < 4; ++i)
          gl16(triK + mOff + p1 + tSrc[i], Tb[cb ^ 1] + tLds[i]);
        #pragma unroll
        for (int i = 0; i < 4; ++i)
          gl16(predB + p1 + pSrc[i], Pb[cb ^ 1] + pLds[i]);
      }
      const unsigned short* predS = (const unsigned short*)Pb[cb];
      const unsigned short* triS  = (const unsigned short*)Tb[cb];
      #pragma unroll
      for (int s = 0; s < 4; ++s) {
        const int k8 = 2 * s + h;
        const int rb = (wv << 5) + tl;
        const bf16x8 bp = *(const bf16x8*)(predS + rb * 64 + ((k8 ^ (rb & 7)) << 3));
        #pragma unroll
        for (int mt = 0; mt < 2; ++mt) {
          const int rm = (mt << 5) + tl;
          const int co = rm * 64 + ((k8 ^ (rm & 7)) << 3);
          const bf16x8 a0 = *(const bf16x8*)(triS + co);
          const bf16x8 a1 = *(const bf16x8*)(triS + 2048 + co);  // kf1 at +4096B
          Qacc[0][mt] = __builtin_amdgcn_mfma_f32_32x32x16_bf16(a0, bp, Qacc[0][mt], 0, 0, 0);
          Qacc[1][mt] = __builtin_amdgcn_mfma_f32_32x32x16_bf16(a1, bp, Qacc[1][mt], 0, 0, 0);
        }
      }
      if (ps == 7 && wv >= 2) {  // TOO tail rows [96,160) into dead Tb[0];
        #pragma unroll            // drained by this phase's vmcnt(0)+barrier
        for (int i = 0; i < 4; ++i)
          gl16(tooB + m0 + aSrcT[i], TAIL + aLdsT[i]);
      }
      asm volatile("s_waitcnt vmcnt(0)" ::: "memory");
      __builtin_amdgcn_s_barrier();
    }
    // ---- Phase B: Q -> bf16 -> per-wave LDS (grouped layout), banded MFMA.
    // QS(wv,f) aliases Pb[f] wave slice (dead: all ps reads retired).
    #pragma unroll
    for (int f = 0; f < 2; ++f) {
      unsigned short* QSw = (unsigned short*)(Pb[f] + (wv << 12));
      #pragma unroll
      for (int mt = 0; mt < 2; ++mt)
        #pragma unroll
        for (int rp = 0; rp < 8; ++rp) {
          const int r = rp << 1;
          const int m = (mt << 5) + (r & 3) + ((r >> 2) << 3) + (h << 2);
          const int c8 = m >> 3, ml = m & 7;
          const int rX = (tl & 24) | ((tl ^ c8) & 7);
          const unsigned int pk = (unsigned int)f2bf(Qacc[f][mt][r]) |
                                  ((unsigned int)f2bf(Qacc[f][mt][r + 1]) << 16);
          *(unsigned int*)(QSw + (((c8 << 5) + rX) << 3) + ml) = pk;
        }
    }
    #pragma unroll
    for (int s = 0; s < 4; ++s) {  // K=64 (m) in 4 steps of 16
      const int k8 = 2 * s + h;
      bf16x8 atoo[2];
      #pragma unroll
      for (int ct = 0; ct < 2; ++ct) {
        const int rbase = (wv + ct) << 5;          // too row t' = t0 + rbase + tl
        const int rr = rbase + tl;
        const unsigned short* tb = (rbase < 96)
            ? (const unsigned short*)TOOM + (size_t)rr * 64
            : (const unsigned short*)TAIL + (size_t)(rr - 96) * 64;
        atoo[ct] = *(const bf16x8*)(tb + ((k8 ^ (rr & 7)) << 3));
      }
      const int rqX = (tl & 24) | ((tl ^ k8) & 7);
      #pragma unroll
      for (int f = 0; f < 2; ++f) {
        const bf16x8 bq = *(const bf16x8*)((const unsigned short*)(Pb[f] + (wv << 12)) +
                                           (((k8 << 5) + rqX) << 3));
        #pragma unroll
        for (int ct = 0; ct < 2; ++ct)
          Sacc[f][ct] = __builtin_amdgcn_mfma_f32_32x32x16_bf16(atoo[ct], bq, Sacc[f][ct], 0, 0, 0);
      }
    }
  }
  // ---- extraction: S[c][t], c=(t-tc)+4+2j, tc = t0+32*wv
  __syncthreads();
  const int tglob = t0 + (wv << 5) + tl;
  float* SW = (float*)smem + (wv << 11);  // 8KB per wave
  #pragma unroll
  for (int f = 0; f < 2; ++f) {
    #pragma unroll
    for (int ct = 0; ct < 2; ++ct)
      #pragma unroll
      for (int r = 0; r < 16; ++r) {
        const int cc = (ct << 5) + (r & 3) + ((r >> 2) << 3) + (h << 2);
        SW[(cc << 5) + tl] = Sacc[f][ct][r];
      }
    if (tglob < TR_) {
      #pragma unroll
      for (int jj = 0; jj < 4; ++jj) {
        const int j = (jj << 1) + h;
        const float v = SW[((tl + 4 + 2 * j) << 5) + tl];
        inner[(((size_t)b * NF_ + j) * NF_ + (kf0 + f)) * TR_ + tglob] = v;
      }
    }
  }
}

// ---------------------------------------------------------------------------
// BN partial stats (bf16 proj inputs, stride OPLD_). Deterministic.
// ---------------------------------------------------------------------------
__global__ __launch_bounds__(256) void bn_stats(
    const unsigned short* __restrict__ op, const unsigned short* __restrict__ pp,
    float* __restrict__ partials) {
  const int hh = blockIdx.x, b = blockIdx.y;
  const unsigned short* oprow = op + ((size_t)b * HS_ + hh) * OPLD_;
  const unsigned short* pprow = pp + ((size_t)b * HS_ + hh) * OPLD_;
  float s = 0.f, s2 = 0.f;
  for (int t = threadIdx.x; t < TR_; t += 256) {
    const float pv = bf2f(pprow[t]);
    #pragma unroll
    for (int j = 0; j < NF_; ++j) {
      float r = bf2f(oprow[t + 2 * j]) + pv;
      r = fmaxf(r, 0.f);
      s += r; s2 += r * r;
    }
  }
  __shared__ float red[256], red2[256];
  red[threadIdx.x] = s; red2[threadIdx.x] = s2;
  __syncthreads();
  for (int st = 128; st > 0; st >>= 1) {
    if (threadIdx.x < st) {
      red[threadIdx.x]  += red[threadIdx.x + st];
      red2[threadIdx.x] += red2[threadIdx.x + st];
    }
    __syncthreads();
  }
  if (threadIdx.x == 0) {
    partials[b * HS_ + hh]            = red[0];
    partials[B_ * HS_ + b * HS_ + hh] = red2[0];
  }
}

__global__ __launch_bounds__(256) void bn_finalize(
    const float* __restrict__ partials, const float* __restrict__ gamma,
    const float* __restrict__ beta, const float* __restrict__ w_out,
    const float* __restrict__ b_out, float* __restrict__ w_eff,
    float* __restrict__ cvec) {
  const int hh = threadIdx.x;
  float s = 0.f, s2 = 0.f;
  for (int b = 0; b < B_; ++b) {
    s  += partials[b * HS_ + hh];
    s2 += partials[B_ * HS_ + b * HS_ + hh];
  }
  const float cnt  = (float)B_ * NF_ * TR_;
  const float mean = s / cnt;
  const float var  = s2 / cnt - mean * mean;
  const float scale = gamma[hh] * rsqrtf(var + EPS_);
  const float shift = beta[hh] - mean * scale;
  #pragma unroll
  for (int k = 0; k < NF_; ++k) w_eff[k * HS_ + hh] = w_out[k * HS_ + hh] * scale;
  __shared__ float red[256];
  for (int k = 0; k < NF_; ++k) {
    red[hh] = w_out[k * HS_ + hh] * shift;
    __syncthreads();
    for (int st = 128; st > 0; st >>= 1) {
      if (hh < st) red[hh] += red[hh + st];
      __syncthreads();
    }
    if (hh == 0) cvec[k] = b_out[k] + red[0];
    __syncthreads();
  }
}

// ---------------------------------------------------------------------------
// head + log-softmax diagonal, fused. One block per (t-chunk 256, b, j-half).
// ---------------------------------------------------------------------------
__global__ __launch_bounds__(256) void head_final(
    const unsigned short* __restrict__ op, const unsigned short* __restrict__ pp,
    const float* __restrict__ w_eff, const float* __restrict__ cvec,
    const float* __restrict__ inner, float* __restrict__ part3) {
  __shared__ float opS[288 * 20];  // [col][hh] col=t-t0 in [0,288)
  __shared__ float ppS[256 * 20];
  __shared__ float weS[8][256];
  __shared__ float red[4][5];
  const int tid = threadIdx.x;
  const int t0 = blockIdx.x * 256;
  const int b  = blockIdx.y;
  const int jh = blockIdx.z;  // j half
  for (int i = tid; i < 8 * 256; i += 256) weS[i >> 8][i & 255] = w_eff[i];
  float acc[4][8] = {};
  const unsigned short* opb = op + (size_t)b * HS_ * OPLD_;
  const unsigned short* ppb = pp + (size_t)b * HS_ * OPLD_;
  for (int hc = 0; hc < 16; ++hc) {
    const int h0 = hc << 4;
    __syncthreads();
    for (int idx = tid; idx < 576; idx += 256) {
      const int r = idx / 36, cc = (idx - r * 36) << 3;
      const int g = min(t0 + cc, OPLD_ - 8);
      uint4 v = *(const uint4*)(opb + (size_t)(h0 + r) * OPLD_ + g);
      #pragma unroll
      for (int e = 0; e < 4; ++e) {
        const unsigned int u = (&v.x)[e];
        opS[(cc + 2 * e) * 20 + r]     = bf2f((unsigned short)(u & 0xffffu));
        opS[(cc + 2 * e + 1) * 20 + r] = bf2f((unsigned short)(u >> 16));
      }
    }
    for (int idx = tid; idx < 512; idx += 256) {
      const int r = idx >> 5, cc = (idx & 31) << 3;
      uint4 v = *(const uint4*)(ppb + (size_t)(h0 + r) * OPLD_ + t0 + cc);
      #pragma unroll
      for (int e = 0; e < 4; ++e) {
        const unsigned int u = (&v.x)[e];
        ppS[(cc + 2 * e) * 20 + r]     = bf2f((unsigned short)(u & 0xffffu));
        ppS[(cc + 2 * e + 1) * 20 + r] = bf2f((unsigned short)(u >> 16));
      }
    }
    __syncthreads();
    float pv[16];
    #pragma unroll
    for (int i = 0; i < 4; ++i) {
      float4 q = *(const float4*)(ppS + tid * 20 + 4 * i);
      pv[4 * i + 0] = q.x; pv[4 * i + 1] = q.y;
      pv[4 * i + 2] = q.z; pv[4 * i + 3] = q.w;
    }
    #pragma unroll
    for (int jj = 0; jj < 4; ++jj) {
      const int col = tid + 2 * ((jh << 2) + jj);
      #pragma unroll
      for (int i = 0; i < 4; ++i) {
        float4 ov = *(const float4*)(opS + col * 20 + 4 * i);
        #pragma unroll
        for (int e = 0; e < 4; ++e) {
          const float r = fmaxf((&ov.x)[e] + pv[4 * i + e], 0.f);
          #pragma unroll
          for (int k = 0; k < 8; ++k) acc[jj][k] += weS[k][h0 + 4 * i + e] * r;
        }
      }
    }
  }
  const int t = t0 + tid;
  float sj[4];
  #pragma unroll
  for (int jj = 0; jj < 4; ++jj) {
    if (t < TR_) {
      const int j = (jh << 2) + jj;
      float v[8]; float mx = -1e30f;
      #pragma unroll
      for (int k = 0; k < 8; ++k) {
        v[k] = acc[jj][k] + cvec[k] +
               inner[(((size_t)b * NF_ + j) * NF_ + k) * TR_ + t];
        mx = fmaxf(mx, v[k]);
      }
      float se = 0.f;
      #pragma unroll
      for (int k = 0; k < 8; ++k) se += expf(v[k] - mx);
      sj[jj] = v[j] - mx - logf(se);
    } else sj[jj] = 0.f;
  }
  #pragma unroll
  for (int jj = 0; jj < 4; ++jj)
    #pragma unroll
    for (int off = 32; off > 0; off >>= 1) sj[jj] += __shfl_down(sj[jj], off);
  if ((tid & 63) == 0) {
    const int wv = tid >> 6;
    #pragma unroll
    for (int jj = 0; jj < 4; ++jj) red[jj][wv] = sj[jj];
  }
  __syncthreads();
  if (tid < 4) {
    const float s = red[tid][0] + red[tid][1] + red[tid][2] + red[tid][3];
    const int j = (jh << 2) + tid;
    part3[(j * B_ + b) * 8 + blockIdx.x] = s;
  }
}

__global__ void final_out(const float* __restrict__ part3, float* __restrict__ out) {
  const int j = threadIdx.x;
  if (j < NF_) {
    float s = 0.f;
    for (int i = 0; i < B_ * 8; ++i) s += part3[j * B_ * 8 + i];
    out[j] = s / ((float)B_ * (float)TR_);
  }
}

// ---------------------------------------------------------------------------
extern "C" void kernel_launch(void* const* d_in, const int* in_sizes, int n_in,
                              void* d_out, int out_size, void* d_ws, size_t ws_size,
                              hipStream_t stream) {
  const float* predictor = (const float*)d_in[0];
  const float* to_order  = (const float*)d_in[1];
  const float* trilinear = (const float*)d_in[2];
  const float* w_o   = (const float*)d_in[3];
  const float* b_o   = (const float*)d_in[4];
  const float* w_p   = (const float*)d_in[5];
  const float* b_p   = (const float*)d_in[6];
  const float* bn_g  = (const float*)d_in[7];
  const float* bn_b  = (const float*)d_in[8];
  const float* w_out = (const float*)d_in[9];
  const float* b_out = (const float*)d_in[10];
  float* out = (float*)d_out;

  char* w = (char*)d_ws;
  unsigned short* pred_t = (unsigned short*)w; w += (size_t)B_ * T_ * NP_ * 2;
  unsigned short* too_t  = (unsigned short*)w; w += (size_t)B_ * T_ * NO_ * 2;
  unsigned short* tri_bf = (unsigned short*)w; w += (size_t)NF_ * NO_ * NP_ * 2;
  unsigned short* wo_bf  = (unsigned short*)w; w += (size_t)HS_ * NO_ * 2;
  unsigned short* wp_bf  = (unsigned short*)w; w += (size_t)HS_ * NP_ * 2;
  unsigned short* o_proj = (unsigned short*)w; w += (size_t)B_ * HS_ * OPLD_ * 2;
  unsigned short* p_proj = (unsigned short*)w; w += (size_t)B_ * HS_ * OPLD_ * 2;
  float* inner    = (float*)w; w += (size_t)B_ * NF_ * NF_ * TR_ * 4;
  float* partials = (float*)w; w += (size_t)2 * B_ * HS_ * 4;
  float* w_eff    = (float*)w; w += (size_t)NF_ * HS_ * 4;
  float* cvec     = (float*)w; w += 256;
  float* part3    = (float*)w; w += (size_t)NF_ * B_ * 8 * 4;

  transpose_cvt<<<dim3(32, 8, 16), 256, 0, stream>>>(predictor, pred_t);
  transpose_cvt<<<dim3(32, 8, 16), 256, 0, stream>>>(to_order, too_t);
  cvt_bf16<<<2048, 256, 0, stream>>>(trilinear, tri_bf, NF_ * NO_ * NP_);
  cvt_bf16<<<128, 256, 0, stream>>>(w_o, wo_bf, HS_ * NO_);
  cvt_bf16<<<128, 256, 0, stream>>>(w_p, wp_bf, HS_ * NP_);

  proj_mfma<<<dim3(16, 2, 16), 256, 0, stream>>>(wo_bf, too_t, b_o, o_proj, TO_, 4);
  proj_mfma<<<dim3(16, 2, 16), 256, 0, stream>>>(wp_bf, pred_t, b_p, p_proj, TR_, 0);

  inner_mfma<<<dim3(16, 4, 16), 256, 0, stream>>>(pred_t, too_t, tri_bf, inner);

  bn_stats<<<dim3(HS_, B_), 256, 0, stream>>>(o_proj, p_proj, partials);
  bn_finalize<<<1, 256, 0, stream>>>(partials, bn_g, bn_b, w_out, b_out, w_eff, cvec);
  head_final<<<dim3(8, B_, 2), 256, 0, stream>>>(o_proj, p_proj, w_eff, cvec, inner, part3);
  final_out<<<1, 64, 0, stream>>>(part3, out);
}